// Round 11
// baseline (81.008 us; speedup 1.0000x reference)
//
#include <hip/hip_runtime.h>

// Causal flash-attention forward. B=4, L=2048, H=8, E=64, fp32 in/out.
// Layout: [B, L, H, E] -> ((b*L + l)*H + h)*E + e ; row stride H*E = 512 floats.
//
// prepass: K and V^T -> f16 tiles in d_ws in FRAGMENT-CONSUMPTION order
//   (frag j of a 64x64 tile at tile_base + j*1024 + lane*16).
// main: 256-thread blocks (4 waves, NO barriers, no LDS), all 4 waves on the
//   SAME 64-row q-tile walking the SAME kv tiles (identical addrs -> L1 hits).
//   DEPTH-2 CHUNK PIPELINE: four 2x-uint4 rolling buffers (ka/kb/va/vb, 32
//   regs total) -- even 16-kv chunks in A, odd in B; each chunk re-issues its
//   buffer's load for chunk c+2 right after the MFMAs consume it. Live state
//   ~78 VGPR -> fits launch_bounds(256,3) with ZERO spill (R7-R10 all spilled;
//   check: WRITE_SIZE == 16384 KB). Static-max softmax (m=8 exp2-units,
//   per-chunk __any trigger + slow path); plain (non-nt) output stores.

#define Bc 4
#define Lc 2048
#define Hc 8
#define Ec 64
#define TILEB 8192
#define NKV 32
#define BHB ((size_t)NKV * TILEB)      // 256 KB per bh
#define WSV ((size_t)32 * BHB)         // V images at +8 MB

using f32x4 = __attribute__((ext_vector_type(4))) float;
using f16x8 = __attribute__((ext_vector_type(8))) _Float16;
using f16x4 = __attribute__((ext_vector_type(4))) _Float16;
using hf16x2 = __fp16 __attribute__((ext_vector_type(2)));
using u32x4 = __attribute__((ext_vector_type(4))) unsigned int;

static __device__ __forceinline__ unsigned int pk2(float lo, float hi) {
    union { hf16x2 h; unsigned int u; } c;
    c.h = __builtin_amdgcn_cvt_pkrtz(lo, hi);
    return c.u;
}
static __device__ __forceinline__ u32x4 nt16(const void* p) {
    return __builtin_nontemporal_load((const u32x4*)p);
}

// ---------------- prepass: fp32 -> f16 fragment-ordered tile images ----------
__global__ __launch_bounds__(256)
void prep_kernel(const float* __restrict__ K, const float* __restrict__ V,
                 char* __restrict__ ws)
{
    __shared__ char kst[64 * 128];
    __shared__ char vst[64 * 144];
    __shared__ char vtt[64 * 128];

    const int bid = blockIdx.x;
    const int bh = bid >> 5, kt = bid & 31;
    const int b = bh >> 3, h = bh & 7;
    const int tid = threadIdx.x;
    const size_t base = (size_t)b * Lc * Hc * Ec + (size_t)h * Ec;

    {   // phase A: load (nontemporal - read once) + convert rows
        const int r = tid >> 2, q4 = tid & 3, c0 = 16 * q4;
        const float* kp = K + base + (size_t)(kt * 64 + r) * 512 + c0;
        const float* vp = V + base + (size_t)(kt * 64 + r) * 512 + c0;
        unsigned int wk[8], wv[8];
        #pragma unroll
        for (int i = 0; i < 4; ++i) {
            union { u32x4 v; float f[4]; } fk, fv;
            fk.v = nt16(kp + 4 * i);
            fv.v = nt16(vp + 4 * i);
            wk[2*i]   = pk2(fk.f[0], fk.f[1]); wk[2*i+1] = pk2(fk.f[2], fk.f[3]);
            wv[2*i]   = pk2(fv.f[0], fv.f[1]); wv[2*i+1] = pk2(fv.f[2], fv.f[3]);
        }
        *(uint4*)(kst + r * 128 + 2 * c0)      = *(uint4*)&wk[0];
        *(uint4*)(kst + r * 128 + 2 * c0 + 16) = *(uint4*)&wk[4];
        *(uint4*)(vst + r * 144 + 2 * c0)      = *(uint4*)&wv[0];
        *(uint4*)(vst + r * 144 + 2 * c0 + 16) = *(uint4*)&wv[4];
    }
    __syncthreads();
    {   // phase B: transpose V -> V^T
        const int e = tid >> 2, kq = tid & 3, kv0 = 16 * kq;
        unsigned int w[8];
        #pragma unroll
        for (int i = 0; i < 8; ++i) {
            unsigned int lo = *(const unsigned short*)(vst + (kv0 + 2*i)     * 144 + 2*e);
            unsigned int hi = *(const unsigned short*)(vst + (kv0 + 2*i + 1) * 144 + 2*e);
            w[i] = lo | (hi << 16);
        }
        *(uint4*)(vtt + e * 128 + 2 * kv0)      = *(uint4*)&w[0];
        *(uint4*)(vtt + e * 128 + 2 * kv0 + 16) = *(uint4*)&w[4];
    }
    __syncthreads();
    {   // phase C: emit fragment-ordered images
        const int lane = tid & 63, qq = tid >> 6;
        const int l15 = lane & 15, l4 = lane >> 4;
        char* ko = ws + (size_t)bh * BHB + (size_t)kt * TILEB;
        char* vo = ws + WSV + (size_t)bh * BHB + (size_t)kt * TILEB;
        uint4 k0 = *(const uint4*)(kst + (16 * qq + l15) * 128 + 16 * l4);
        uint4 k1 = *(const uint4*)(kst + (16 * qq + l15) * 128 + 64 + 16 * l4);
        *(uint4*)(ko + (2 * qq)     * 1024 + lane * 16) = k0;
        *(uint4*)(ko + (2 * qq + 1) * 1024 + lane * 16) = k1;
        unsigned long long vv[4];
        #pragma unroll
        for (int c = 0; c < 4; ++c)
            vv[c] = *(const unsigned long long*)(vtt + (16 * c + l15) * 128 + 32 * qq + 8 * l4);
        uint4 v01, v23;
        v01.x = (unsigned)vv[0]; v01.y = (unsigned)(vv[0] >> 32);
        v01.z = (unsigned)vv[1]; v01.w = (unsigned)(vv[1] >> 32);
        v23.x = (unsigned)vv[2]; v23.y = (unsigned)(vv[2] >> 32);
        v23.z = (unsigned)vv[3]; v23.w = (unsigned)(vv[3] >> 32);
        *(uint4*)(vo + (2 * qq)     * 1024 + lane * 16) = v01;
        *(uint4*)(vo + (2 * qq + 1) * 1024 + lane * 16) = v23;
    }
}

// one 16-kv chunk: QK MFMA -> reissue K buffer load -> mask/softmax -> PV ->
// reissue V buffer load. All buffer indices compile-time (no scratch).
static __device__ __forceinline__ void do_chunk(
    uint4* kb2, uint4* vb2, const char* kpre, const char* vpre,
    const f16x8& qa0, const f16x8& qa1, f32x4* o, float& lsum, float& m_run,
    int kvbase, int q_g, bool last, int l4)
{
    union { uint4 u; f16x8 h; } a0, a1;
    a0.u = kb2[0]; a1.u = kb2[1];
    f32x4 s = {0.f, 0.f, 0.f, 0.f};
    s = __builtin_amdgcn_mfma_f32_16x16x32_f16(a0.h, qa0, s, 0, 0, 0);
    s = __builtin_amdgcn_mfma_f32_16x16x32_f16(a1.h, qa1, s, 0, 0, 0);

    kb2[0] = *(const uint4*)(kpre);           // prefetch chunk c+2 (K)
    kb2[1] = *(const uint4*)(kpre + 1024);

    if (last) {
        #pragma unroll
        for (int r2 = 0; r2 < 4; ++r2)
            if (kvbase + 4 * l4 + r2 > q_g) s[r2] = -1e30f;
    }

    const float cmax = fmaxf(fmaxf(s[0], s[1]), fmaxf(s[2], s[3]));
    if (__any(cmax > m_run)) {                // slow path: never for N(0,1) data
        float pm = cmax;
        pm = fmaxf(pm, __shfl_xor(pm, 16, 64));
        pm = fmaxf(pm, __shfl_xor(pm, 32, 64));
        const float m_new = fmaxf(m_run, pm);
        const float fac = __builtin_exp2f(m_run - m_new);
        m_run = m_new;
        lsum *= fac;
        float fr[4];
        #pragma unroll
        for (int r2 = 0; r2 < 4; ++r2) fr[r2] = __shfl(fac, 4 * l4 + r2, 64);
        #pragma unroll
        for (int c = 0; c < 4; ++c)
            #pragma unroll
            for (int r2 = 0; r2 < 4; ++r2) o[c][r2] *= fr[r2];
    }

    const float p0 = __builtin_exp2f(s[0] - m_run);
    const float p1 = __builtin_exp2f(s[1] - m_run);
    const float p2 = __builtin_exp2f(s[2] - m_run);
    const float p3 = __builtin_exp2f(s[3] - m_run);
    lsum += (p0 + p1) + (p2 + p3);
    union { f16x4 h; unsigned int u[2]; } pa;
    pa.u[0] = pk2(p0, p1);
    pa.u[1] = pk2(p2, p3);

    union { uint4 u; f16x4 h[2]; } w0, w1;
    w0.u = vb2[0]; w1.u = vb2[1];
    o[0] = __builtin_amdgcn_mfma_f32_16x16x16f16(pa.h, w0.h[0], o[0], 0, 0, 0);
    o[1] = __builtin_amdgcn_mfma_f32_16x16x16f16(pa.h, w0.h[1], o[1], 0, 0, 0);
    o[2] = __builtin_amdgcn_mfma_f32_16x16x16f16(pa.h, w1.h[0], o[2], 0, 0, 0);
    o[3] = __builtin_amdgcn_mfma_f32_16x16x16f16(pa.h, w1.h[1], o[3], 0, 0, 0);

    vb2[0] = *(const uint4*)(vpre);           // prefetch chunk c+2 (V)
    vb2[1] = *(const uint4*)(vpre + 1024);
}

// ---- main: 4 waves/block, no barriers, depth-2 chunk pipeline, no spill ----
__global__ __launch_bounds__(256, 3)
void fa_fwd_kernel(const float* __restrict__ Q, const char* __restrict__ ws,
                   float* __restrict__ Out)
{
    const int bid = blockIdx.x;
    const int qi  = bid >> 5;                 // 0..31
    const int bh  = bid & 31;
    const int qt  = 31 - qi;                  // longest q-tiles first
    const int b   = bh >> 3, h = bh & 7;

    const int tid  = threadIdx.x;
    const int wid  = tid >> 6;                // 0..3
    const int lane = tid & 63;
    const int l15  = lane & 15, l4 = lane >> 4;

    const size_t base = (size_t)b * Lc * Hc * Ec + (size_t)h * Ec;
    const char* kimg = ws + (size_t)bh * BHB + lane * 16;
    const char* vimg = ws + WSV + (size_t)bh * BHB + lane * 16;
    const float SL2E = 0.125f * 1.44269504088896340736f;

    const int qrow0 = qt * 64 + 16 * wid;
    const int mysteps = qt + 1;               // uniform within block
    const int q_g = qrow0 + l15;

    // Q fragment (B-operand, 16 rows), nontemporal, prescaled by scale*log2e
    f16x8 qa0, qa1;
    {
        const float* qpr = Q + base + (size_t)q_g * 512 + 8 * l4;
        union { u32x4 v; float f[4]; } f0, f1, f2, f3;
        f0.v = nt16(qpr);      f1.v = nt16(qpr + 4);
        f2.v = nt16(qpr + 32); f3.v = nt16(qpr + 36);
        union { f16x8 v; unsigned int u[4]; } pk;
        pk.u[0] = pk2(f0.f[0] * SL2E, f0.f[1] * SL2E);
        pk.u[1] = pk2(f0.f[2] * SL2E, f0.f[3] * SL2E);
        pk.u[2] = pk2(f1.f[0] * SL2E, f1.f[1] * SL2E);
        pk.u[3] = pk2(f1.f[2] * SL2E, f1.f[3] * SL2E);
        qa0 = pk.v;
        pk.u[0] = pk2(f2.f[0] * SL2E, f2.f[1] * SL2E);
        pk.u[1] = pk2(f2.f[2] * SL2E, f2.f[3] * SL2E);
        pk.u[2] = pk2(f3.f[0] * SL2E, f3.f[1] * SL2E);
        pk.u[3] = pk2(f3.f[2] * SL2E, f3.f[3] * SL2E);
        qa1 = pk.v;
    }

    f32x4 o[4] = {};
    float lsum = 0.f;                 // per-lane partial row-sum of P
    float m_run = 8.0f;               // static max bound (exp2 units)

    // rolling chunk buffers: even chunks in *a, odd chunks in *b
    uint4 ka[2], kb[2], va[2], vb[2];
    ka[0] = *(const uint4*)(kimg);        ka[1] = *(const uint4*)(kimg + 1024);
    kb[0] = *(const uint4*)(kimg + 2048); kb[1] = *(const uint4*)(kimg + 3072);
    va[0] = *(const uint4*)(vimg);        va[1] = *(const uint4*)(vimg + 1024);
    vb[0] = *(const uint4*)(vimg + 2048); vb[1] = *(const uint4*)(vimg + 3072);

    #pragma unroll 1
    for (int kt = 0; kt < mysteps; ++kt) {
        const bool last = (kt == mysteps - 1);
        const char* kt_k = kimg + (size_t)kt * TILEB;
        const char* kt_v = vimg + (size_t)kt * TILEB;
        const char* nk = last ? kimg : (kt_k + TILEB);   // clamp: harmless reload
        const char* nv = last ? vimg : (kt_v + TILEB);
        const int kv0 = kt * 64;

        do_chunk(ka, va, kt_k + 4096, kt_v + 4096, qa0, qa1, o, lsum, m_run, kv0,      q_g, last, l4);
        do_chunk(kb, vb, kt_k + 6144, kt_v + 6144, qa0, qa1, o, lsum, m_run, kv0 + 16, q_g, last, l4);
        do_chunk(ka, va, nk,          nv,          qa0, qa1, o, lsum, m_run, kv0 + 32, q_g, last, l4);
        do_chunk(kb, vb, nk + 2048,   nv + 2048,   qa0, qa1, o, lsum, m_run, kv0 + 48, q_g, last, l4);
    }

    // epilogue: finish l (sum over l4 groups), normalize, plain fp32 stores
    lsum += __shfl_xor(lsum, 16, 64);
    lsum += __shfl_xor(lsum, 32, 64);
    const float inv = 1.0f / lsum;            // lives in q = l15 domain
    float ir[4];
    #pragma unroll
    for (int r2 = 0; r2 < 4; ++r2) ir[r2] = __shfl(inv, 4 * l4 + r2, 64);
    float* op = Out + base;
    #pragma unroll
    for (int c = 0; c < 4; ++c)
        #pragma unroll
        for (int r2 = 0; r2 < 4; ++r2)
            op[(size_t)(qrow0 + 4 * l4 + r2) * 512 + 16 * c + l15] = o[c][r2] * ir[r2];
}

extern "C" void kernel_launch(void* const* d_in, const int* in_sizes, int n_in,
                              void* d_out, int out_size, void* d_ws, size_t ws_size,
                              hipStream_t stream) {
    const float* Q = (const float*)d_in[0];
    const float* K = (const float*)d_in[1];
    const float* V = (const float*)d_in[2];
    float* O = (float*)d_out;
    char* ws = (char*)d_ws;   // 16 MB fragment-ordered tile images
    hipLaunchKernelGGL(prep_kernel, dim3(32 * NKV), dim3(256), 0, stream, K, V, ws);
    hipLaunchKernelGGL(fa_fwd_kernel, dim3(32 * 32), dim3(256), 0, stream, Q, ws, O);
}

// Round 12
// 69.373 us; speedup vs baseline: 1.1677x; 1.1677x over previous
//
#include <hip/hip_runtime.h>

// Causal flash-attention forward. B=4, L=2048, H=8, E=64, fp32 in/out.
// Layout: [B, L, H, E] -> ((b*L + l)*H + h)*E + e ; row stride H*E = 512 floats.
//
// prepass: K and V^T -> f16 tiles in d_ws in FRAGMENT-CONSUMPTION order
//   (frag j of a 64x64 tile at tile_base + j*1024 + lane*16).
// main: 256-thread blocks (4 waves, NO barriers, no LDS). Each wave owns 32
//   q-rows as TWO 16-row fragment sets; the block's 4 waves (128 q-rows) walk
//   the SAME kv tiles reading IDENTICAL addresses. vs R8 this halves VMEM
//   bytes per unit work (the R11 finding: bound = per-CU vector-L1 return BW).
//   Full-tile register lookahead (prefetch chunk m of tile kt+1 right after
//   chunk m of kt is consumed -- R8's proven depth; R11's 2-chunk was too
//   shallow). Static-max softmax (m=8 exp2-units, __any guard + slow path).
//   launch_bounds(256,2) -> VGPR cap 128, no spill (check WRITE_SIZE==16384).
//   Grid 512 = 2 blocks/CU fully resident; qi->qt pairs to constant CU work.

#define Bc 4
#define Lc 2048
#define Hc 8
#define Ec 64
#define TILEB 8192
#define NKV 32
#define BHB ((size_t)NKV * TILEB)      // 256 KB per bh
#define WSV ((size_t)32 * BHB)         // V images at +8 MB

using f32x4 = __attribute__((ext_vector_type(4))) float;
using f16x8 = __attribute__((ext_vector_type(8))) _Float16;
using f16x4 = __attribute__((ext_vector_type(4))) _Float16;
using hf16x2 = __fp16 __attribute__((ext_vector_type(2)));
using u32x4 = __attribute__((ext_vector_type(4))) unsigned int;

static __device__ __forceinline__ unsigned int pk2(float lo, float hi) {
    union { hf16x2 h; unsigned int u; } c;
    c.h = __builtin_amdgcn_cvt_pkrtz(lo, hi);
    return c.u;
}
static __device__ __forceinline__ u32x4 nt16(const void* p) {
    return __builtin_nontemporal_load((const u32x4*)p);
}

// ---------------- prepass: fp32 -> f16 fragment-ordered tile images ----------
__global__ __launch_bounds__(256)
void prep_kernel(const float* __restrict__ K, const float* __restrict__ V,
                 char* __restrict__ ws)
{
    __shared__ char kst[64 * 128];
    __shared__ char vst[64 * 144];
    __shared__ char vtt[64 * 128];

    const int bid = blockIdx.x;
    const int bh = bid >> 5, kt = bid & 31;
    const int b = bh >> 3, h = bh & 7;
    const int tid = threadIdx.x;
    const size_t base = (size_t)b * Lc * Hc * Ec + (size_t)h * Ec;

    {   // phase A: load (nontemporal - read once) + convert rows
        const int r = tid >> 2, q4 = tid & 3, c0 = 16 * q4;
        const float* kp = K + base + (size_t)(kt * 64 + r) * 512 + c0;
        const float* vp = V + base + (size_t)(kt * 64 + r) * 512 + c0;
        unsigned int wk[8], wv[8];
        #pragma unroll
        for (int i = 0; i < 4; ++i) {
            union { u32x4 v; float f[4]; } fk, fv;
            fk.v = nt16(kp + 4 * i);
            fv.v = nt16(vp + 4 * i);
            wk[2*i]   = pk2(fk.f[0], fk.f[1]); wk[2*i+1] = pk2(fk.f[2], fk.f[3]);
            wv[2*i]   = pk2(fv.f[0], fv.f[1]); wv[2*i+1] = pk2(fv.f[2], fv.f[3]);
        }
        *(uint4*)(kst + r * 128 + 2 * c0)      = *(uint4*)&wk[0];
        *(uint4*)(kst + r * 128 + 2 * c0 + 16) = *(uint4*)&wk[4];
        *(uint4*)(vst + r * 144 + 2 * c0)      = *(uint4*)&wv[0];
        *(uint4*)(vst + r * 144 + 2 * c0 + 16) = *(uint4*)&wv[4];
    }
    __syncthreads();
    {   // phase B: transpose V -> V^T
        const int e = tid >> 2, kq = tid & 3, kv0 = 16 * kq;
        unsigned int w[8];
        #pragma unroll
        for (int i = 0; i < 8; ++i) {
            unsigned int lo = *(const unsigned short*)(vst + (kv0 + 2*i)     * 144 + 2*e);
            unsigned int hi = *(const unsigned short*)(vst + (kv0 + 2*i + 1) * 144 + 2*e);
            w[i] = lo | (hi << 16);
        }
        *(uint4*)(vtt + e * 128 + 2 * kv0)      = *(uint4*)&w[0];
        *(uint4*)(vtt + e * 128 + 2 * kv0 + 16) = *(uint4*)&w[4];
    }
    __syncthreads();
    {   // phase C: emit fragment-ordered images
        const int lane = tid & 63, qq = tid >> 6;
        const int l15 = lane & 15, l4 = lane >> 4;
        char* ko = ws + (size_t)bh * BHB + (size_t)kt * TILEB;
        char* vo = ws + WSV + (size_t)bh * BHB + (size_t)kt * TILEB;
        uint4 k0 = *(const uint4*)(kst + (16 * qq + l15) * 128 + 16 * l4);
        uint4 k1 = *(const uint4*)(kst + (16 * qq + l15) * 128 + 64 + 16 * l4);
        *(uint4*)(ko + (2 * qq)     * 1024 + lane * 16) = k0;
        *(uint4*)(ko + (2 * qq + 1) * 1024 + lane * 16) = k1;
        unsigned long long vv[4];
        #pragma unroll
        for (int c = 0; c < 4; ++c)
            vv[c] = *(const unsigned long long*)(vtt + (16 * c + l15) * 128 + 32 * qq + 8 * l4);
        uint4 v01, v23;
        v01.x = (unsigned)vv[0]; v01.y = (unsigned)(vv[0] >> 32);
        v01.z = (unsigned)vv[1]; v01.w = (unsigned)(vv[1] >> 32);
        v23.x = (unsigned)vv[2]; v23.y = (unsigned)(vv[2] >> 32);
        v23.z = (unsigned)vv[3]; v23.w = (unsigned)(vv[3] >> 32);
        *(uint4*)(vo + (2 * qq)     * 1024 + lane * 16) = v01;
        *(uint4*)(vo + (2 * qq + 1) * 1024 + lane * 16) = v23;
    }
}

// ---- main: 4 waves/block, 2 q-sets/wave, no barriers, full-tile lookahead ---
__global__ __launch_bounds__(256, 2)
void fa_fwd_kernel(const float* __restrict__ Q, const char* __restrict__ ws,
                   float* __restrict__ Out)
{
    const int bid = blockIdx.x;
    const int qi  = bid >> 5;                 // 0..15
    const int bh  = bid & 31;
    // pair (qi, qi+8) -> (15-c, c): constant work if those share a CU slot
    const int qt  = (qi < 8) ? (15 - qi) : (qi - 8);
    const int b   = bh >> 3, h = bh & 7;

    const int tid  = threadIdx.x;
    const int wid  = tid >> 6;                // 0..3
    const int lane = tid & 63;
    const int l15  = lane & 15, l4 = lane >> 4;

    const size_t base = (size_t)b * Lc * Hc * Ec + (size_t)h * Ec;
    const char* kimg = ws + (size_t)bh * BHB + lane * 16;
    const char* vimg = ws + WSV + (size_t)bh * BHB + lane * 16;
    const float SL2E = 0.125f * 1.44269504088896340736f;

    const int qrow0 = qt * 128 + 32 * wid;    // wave's 32 q-rows
    const int mysteps = 2 * qt + 1 + (wid >> 1);   // own causal extent

    // Q fragments for both 16-row sets, nontemporal, prescaled by scale*log2e
    f16x8 qa[2][2];
    #pragma unroll
    for (int g = 0; g < 2; ++g) {
        const float* qpr = Q + base + (size_t)(qrow0 + 16 * g + l15) * 512 + 8 * l4;
        union { u32x4 v; float f[4]; } f0, f1, f2, f3;
        f0.v = nt16(qpr);      f1.v = nt16(qpr + 4);
        f2.v = nt16(qpr + 32); f3.v = nt16(qpr + 36);
        union { f16x8 v; unsigned int u[4]; } pk;
        pk.u[0] = pk2(f0.f[0] * SL2E, f0.f[1] * SL2E);
        pk.u[1] = pk2(f0.f[2] * SL2E, f0.f[3] * SL2E);
        pk.u[2] = pk2(f1.f[0] * SL2E, f1.f[1] * SL2E);
        pk.u[3] = pk2(f1.f[2] * SL2E, f1.f[3] * SL2E);
        qa[g][0] = pk.v;
        pk.u[0] = pk2(f2.f[0] * SL2E, f2.f[1] * SL2E);
        pk.u[1] = pk2(f2.f[2] * SL2E, f2.f[3] * SL2E);
        pk.u[2] = pk2(f3.f[0] * SL2E, f3.f[1] * SL2E);
        pk.u[3] = pk2(f3.f[2] * SL2E, f3.f[3] * SL2E);
        qa[g][1] = pk.v;
    }

    f32x4 o[2][4] = {};
    float lsum[2] = {0.f, 0.f};
    float m_run[2] = {8.0f, 8.0f};    // static max bound (exp2 units)

    uint4 kf[8], vf[8];
    #pragma unroll
    for (int j = 0; j < 8; ++j) kf[j] = *(const uint4*)(kimg + j * 1024);
    #pragma unroll
    for (int j = 0; j < 8; ++j) vf[j] = *(const uint4*)(vimg + j * 1024);

    #pragma unroll 1
    for (int kt = 0; kt < mysteps; ++kt) {
        const bool last = (kt == mysteps - 1);
        const char* kp = kimg + (size_t)(last ? 0 : kt + 1) * TILEB;   // clamp
        const char* vp = vimg + (size_t)(last ? 0 : kt + 1) * TILEB;
        const int kv0 = kt * 64;

        #pragma unroll
        for (int m = 0; m < 4; ++m) {
            // ---- QK chunk m, both q-sets (K fragments read once, used twice)
            union { uint4 u; f16x8 h; } a0, a1;
            a0.u = kf[2 * m]; a1.u = kf[2 * m + 1];
            f32x4 s[2];
            #pragma unroll
            for (int g = 0; g < 2; ++g) {
                f32x4 z = {0.f, 0.f, 0.f, 0.f};
                z = __builtin_amdgcn_mfma_f32_16x16x32_f16(a0.h, qa[g][0], z, 0, 0, 0);
                z = __builtin_amdgcn_mfma_f32_16x16x32_f16(a1.h, qa[g][1], z, 0, 0, 0);
                s[g] = z;
            }

            // prefetch next-tile K chunk m into the just-freed slots
            kf[2 * m]     = *(const uint4*)(kp + (2 * m)     * 1024);
            kf[2 * m + 1] = *(const uint4*)(kp + (2 * m + 1) * 1024);

            if (last) {   // causal mask (this wave's own diagonal tile)
                #pragma unroll
                for (int g = 0; g < 2; ++g) {
                    const int q_g = qrow0 + 16 * g + l15;
                    #pragma unroll
                    for (int r2 = 0; r2 < 4; ++r2) {
                        const int kv_g = kv0 + 16 * m + 4 * l4 + r2;
                        if (kv_g > q_g) s[g][r2] = -1e30f;
                    }
                }
            }

            // softmax + PV per set
            union { uint4 u; f16x4 h[2]; } w0, w1;
            w0.u = vf[2 * m]; w1.u = vf[2 * m + 1];
            #pragma unroll
            for (int g = 0; g < 2; ++g) {
                const float cmax = fmaxf(fmaxf(s[g][0], s[g][1]),
                                         fmaxf(s[g][2], s[g][3]));
                if (__any(cmax > m_run[g])) {   // slow path: never for N(0,1)
                    float pm = cmax;
                    pm = fmaxf(pm, __shfl_xor(pm, 16, 64));
                    pm = fmaxf(pm, __shfl_xor(pm, 32, 64));
                    const float m_new = fmaxf(m_run[g], pm);
                    const float fac = __builtin_exp2f(m_run[g] - m_new);
                    m_run[g] = m_new;
                    lsum[g] *= fac;
                    float fr[4];
                    #pragma unroll
                    for (int r2 = 0; r2 < 4; ++r2) fr[r2] = __shfl(fac, 4 * l4 + r2, 64);
                    #pragma unroll
                    for (int c = 0; c < 4; ++c)
                        #pragma unroll
                        for (int r2 = 0; r2 < 4; ++r2) o[g][c][r2] *= fr[r2];
                }
                const float p0 = __builtin_exp2f(s[g][0] - m_run[g]);
                const float p1 = __builtin_exp2f(s[g][1] - m_run[g]);
                const float p2 = __builtin_exp2f(s[g][2] - m_run[g]);
                const float p3 = __builtin_exp2f(s[g][3] - m_run[g]);
                lsum[g] += (p0 + p1) + (p2 + p3);
                union { f16x4 h; unsigned int u[2]; } pa;
                pa.u[0] = pk2(p0, p1);
                pa.u[1] = pk2(p2, p3);
                o[g][0] = __builtin_amdgcn_mfma_f32_16x16x16f16(pa.h, w0.h[0], o[g][0], 0, 0, 0);
                o[g][1] = __builtin_amdgcn_mfma_f32_16x16x16f16(pa.h, w0.h[1], o[g][1], 0, 0, 0);
                o[g][2] = __builtin_amdgcn_mfma_f32_16x16x16f16(pa.h, w1.h[0], o[g][2], 0, 0, 0);
                o[g][3] = __builtin_amdgcn_mfma_f32_16x16x16f16(pa.h, w1.h[1], o[g][3], 0, 0, 0);
            }

            // prefetch next-tile V chunk m into the just-freed slots
            vf[2 * m]     = *(const uint4*)(vp + (2 * m)     * 1024);
            vf[2 * m + 1] = *(const uint4*)(vp + (2 * m + 1) * 1024);
        }
    }

    // epilogue: finish l per set, normalize, plain fp32 stores
    float* op = Out + base;
    #pragma unroll
    for (int g = 0; g < 2; ++g) {
        float ls = lsum[g];
        ls += __shfl_xor(ls, 16, 64);
        ls += __shfl_xor(ls, 32, 64);
        const float inv = 1.0f / ls;          // q = l15 domain
        float ir[4];
        #pragma unroll
        for (int r2 = 0; r2 < 4; ++r2) ir[r2] = __shfl(inv, 4 * l4 + r2, 64);
        const int qr = qrow0 + 16 * g;
        #pragma unroll
        for (int c = 0; c < 4; ++c)
            #pragma unroll
            for (int r2 = 0; r2 < 4; ++r2)
                op[(size_t)(qr + 4 * l4 + r2) * 512 + 16 * c + l15] = o[g][c][r2] * ir[r2];
    }
}

extern "C" void kernel_launch(void* const* d_in, const int* in_sizes, int n_in,
                              void* d_out, int out_size, void* d_ws, size_t ws_size,
                              hipStream_t stream) {
    const float* Q = (const float*)d_in[0];
    const float* K = (const float*)d_in[1];
    const float* V = (const float*)d_in[2];
    float* O = (float*)d_out;
    char* ws = (char*)d_ws;   // 16 MB fragment-ordered tile images
    hipLaunchKernelGGL(prep_kernel, dim3(32 * NKV), dim3(256), 0, stream, K, V, ws);
    hipLaunchKernelGGL(fa_fwd_kernel, dim3(16 * 32), dim3(256), 0, stream, Q, ws, O);
}